// Round 19
// baseline (313.338 us; speedup 1.0000x reference)
//
#include <hip/hip_runtime.h>
#include <hip/hip_bf16.h>

#define S 2048
#define HID 4096
#define NH 32
#define NKV 8
#define HD 128
#define QKVN 6144  // NH*HD + 2*NKV*HD

typedef __attribute__((ext_vector_type(8))) short bf16x8;
typedef __attribute__((ext_vector_type(4))) float f32x4;
typedef __attribute__((ext_vector_type(8))) unsigned short u16x8;
typedef __attribute__((ext_vector_type(4))) unsigned short u16x4;

#define GLOAD16(src, dst)                                                        \
  __builtin_amdgcn_global_load_lds(                                              \
      (const __attribute__((address_space(1))) unsigned int*)(src),              \
      (__attribute__((address_space(3))) unsigned int*)(dst), 16, 0, 0)

__device__ __forceinline__ unsigned short f2bf(float f) {
  union { float f; unsigned u; } c; c.f = f;
  unsigned u = c.u;
  return (unsigned short)((u + 0x7FFFu + ((u >> 16) & 1u)) >> 16);
}
__device__ __forceinline__ float bf2f(unsigned short h) {
  union { unsigned u; float f; } c; c.u = ((unsigned)h) << 16;
  return c.f;
}

// ---------------- fp32 -> bf16 convert (vector4) ----------------
__global__ void convert_kernel(const float* __restrict__ in,
                               unsigned short* __restrict__ out, int n4) {
  int i = blockIdx.x * blockDim.x + threadIdx.x;
  if (i < n4) {
    float4 v = ((const float4*)in)[i];
    ushort4 o;
    o.x = f2bf(v.x); o.y = f2bf(v.y); o.z = f2bf(v.z); o.w = f2bf(v.w);
    ((ushort4*)out)[i] = o;
  }
}

// ---------------- merged q/k/v weight transpose+convert -> Wt rows [0,6144) ----------------
__global__ void transpose_qkv(const float* __restrict__ qw,
                              const float* __restrict__ kw,
                              const float* __restrict__ vw,
                              unsigned short* __restrict__ out) {
  __shared__ float tile[32][33];
  int tx = threadIdx.x, ty = threadIdx.y;       // 32 x 8
  int n0 = blockIdx.x * 32, k0 = blockIdx.y * 32;
  const float* in;
  int N, nn;
  if (n0 < NH * HD)                 { in = qw; N = NH * HD;  nn = n0; }
  else if (n0 < (NH + NKV) * HD)    { in = kw; N = NKV * HD; nn = n0 - NH * HD; }
  else                              { in = vw; N = NKV * HD; nn = n0 - (NH + NKV) * HD; }
#pragma unroll
  for (int i = 0; i < 32; i += 8)
    tile[ty + i][tx] = in[(size_t)(k0 + ty + i) * N + nn + tx];
  __syncthreads();
#pragma unroll
  for (int i = 0; i < 32; i += 8)
    out[(size_t)(n0 + ty + i) * HID + k0 + tx] = f2bf(tile[tx][ty + i]);
}

// ---------------- transpose + convert: in [K][N] f32 -> out [N][K=4096] bf16 ----------------
__global__ void transpose_convert(const float* __restrict__ in,
                                  unsigned short* __restrict__ out, int N) {
  __shared__ float tile[32][33];
  int tx = threadIdx.x, ty = threadIdx.y;       // 32 x 8
  int n0 = blockIdx.x * 32, k0 = blockIdx.y * 32;
#pragma unroll
  for (int i = 0; i < 32; i += 8)
    tile[ty + i][tx] = in[(size_t)(k0 + ty + i) * N + n0 + tx];
  __syncthreads();
#pragma unroll
  for (int i = 0; i < 32; i += 8)
    out[(size_t)(n0 + ty + i) * HID + k0 + tx] = f2bf(tile[tx][ty + i]);
}

__device__ __forceinline__ void storeC(unsigned short* C, size_t idx, float v) { C[idx] = f2bf(v); }
__device__ __forceinline__ void storeC(float* C, size_t idx, float v) { C[idx] = v; }

// ---------------- bf16 GEMM 256x128 (v2 structure, 8 waves): O-projection ----------------
// Parameter variant of the r17-proven gemm_qkv: BM=256, BN=128, grid 32x8 = 256 blocks
// = exact 1/CU fill. Wave tile 128x32 (acc[8][2]); A panel [256][64] staged 4 chunks/
// thread (identical to QKV), B panel [128][64] staged 2 chunks/thread. Zero-conflict
// ^(row&7) involution; 1 barrier + 1 vmcnt(0) per tile; 2 k-phases; stage->use 2 phases.
template <typename OutT>
__launch_bounds__(512, 1)
__global__ void gemm_o(const unsigned short* __restrict__ A,
                       const unsigned short* __restrict__ Bt,
                       OutT* __restrict__ C, int K, int ldc) {
  __shared__ unsigned short As[2][256 * 64];   // 64 KB
  __shared__ unsigned short Bs[2][128 * 64];   // 32 KB
  const int tid = threadIdx.x, lane = tid & 63, w = tid >> 6;
  const int wm = w >> 2, wn = w & 3;           // 2M x 4N wave grid
  const int m0 = blockIdx.y * 256, n0 = blockIdx.x * 128;
  const int lq = lane & 15, g = lane >> 4;
  const int sw = lq & 7;

  f32x4 acc[8][2] = {};
  const int NT = K >> 6;

  auto STAGE_PAIR = [&](int bb, int kt) {
#pragma unroll
    for (int i = 0; i < 4; ++i) {              // A: 2048 chunks, 4/thread
      int ci = tid + i * 512;
      int r = ci >> 3;
      int jl = ((ci & 7) ^ (r & 7)) << 3;      // inverse swizzle on source
      GLOAD16(A + (size_t)(m0 + r) * K + kt + jl, &As[bb][ci * 8]);
    }
#pragma unroll
    for (int i = 0; i < 2; ++i) {              // B: 1024 chunks, 2/thread
      int ci = tid + i * 512;
      int r = ci >> 3;
      int jl = ((ci & 7) ^ (r & 7)) << 3;
      GLOAD16(Bt + (size_t)(n0 + r) * K + kt + jl, &Bs[bb][ci * 8]);
    }
  };

  STAGE_PAIR(0, 0);

  for (int t = 0; t < NT; ++t) {
    const int c = t & 1;
    const bool more = (t + 1) < NT;

    // ---- phase 0 (k 0..31) ----
    asm volatile("s_waitcnt vmcnt(0)" ::: "memory");   // pair(t): issued 2 phases ago
    __builtin_amdgcn_s_barrier();
    bf16x8 af[8], bf[2];
#pragma unroll
    for (int mi = 0; mi < 8; ++mi)
      af[mi] = *(const bf16x8*)&As[c][(wm * 128 + mi * 16 + lq) * 64 + ((g ^ sw) << 3)];
#pragma unroll
    for (int ni = 0; ni < 2; ++ni)
      bf[ni] = *(const bf16x8*)&Bs[c][(wn * 32 + ni * 16 + lq) * 64 + ((g ^ sw) << 3)];
    if (more) STAGE_PAIR(c ^ 1, (t + 1) << 6);
    asm volatile("s_waitcnt lgkmcnt(0)" ::: "memory");
    __builtin_amdgcn_sched_barrier(0);
    __builtin_amdgcn_s_setprio(1);
#pragma unroll
    for (int mi = 0; mi < 8; ++mi)
#pragma unroll
      for (int ni = 0; ni < 2; ++ni)
        acc[mi][ni] = __builtin_amdgcn_mfma_f32_16x16x32_bf16(af[mi], bf[ni], acc[mi][ni], 0, 0, 0);
    __builtin_amdgcn_s_setprio(0);

    // ---- phase 1 (k 32..63): same buffer, no barrier/vmcnt needed ----
#pragma unroll
    for (int mi = 0; mi < 8; ++mi)
      af[mi] = *(const bf16x8*)&As[c][(wm * 128 + mi * 16 + lq) * 64 + (((4 + g) ^ sw) << 3)];
#pragma unroll
    for (int ni = 0; ni < 2; ++ni)
      bf[ni] = *(const bf16x8*)&Bs[c][(wn * 32 + ni * 16 + lq) * 64 + (((4 + g) ^ sw) << 3)];
    asm volatile("s_waitcnt lgkmcnt(0)" ::: "memory");
    __builtin_amdgcn_sched_barrier(0);
    __builtin_amdgcn_s_setprio(1);
#pragma unroll
    for (int mi = 0; mi < 8; ++mi)
#pragma unroll
      for (int ni = 0; ni < 2; ++ni)
        acc[mi][ni] = __builtin_amdgcn_mfma_f32_16x16x32_bf16(af[mi], bf[ni], acc[mi][ni], 0, 0, 0);
    __builtin_amdgcn_s_setprio(0);
  }

  // epilogue
#pragma unroll
  for (int mi = 0; mi < 8; ++mi)
#pragma unroll
    for (int ni = 0; ni < 2; ++ni) {
      int row = m0 + wm * 128 + mi * 16 + g * 4;
      int col = n0 + wn * 32 + ni * 16 + lq;
#pragma unroll
      for (int r = 0; r < 4; ++r)
        storeC(C, (size_t)(row + r) * ldc + col, acc[mi][ni][r]);
    }
}

// ---------------- bf16 GEMM 256x192 (r17-proven, 97us): QKV projection ----------------
template <typename OutT>
__launch_bounds__(512, 1)
__global__ void gemm_qkv(const unsigned short* __restrict__ A,
                         const unsigned short* __restrict__ Bt,
                         OutT* __restrict__ C, int K, int ldc) {
  __shared__ unsigned short As[2][256 * 64];   // 64 KB
  __shared__ unsigned short Bs[2][192 * 64];   // 48 KB
  const int tid = threadIdx.x, lane = tid & 63, w = tid >> 6;
  const int wm = w >> 2, wn = w & 3;           // 2M x 4N wave grid
  const int m0 = blockIdx.y * 256, n0 = blockIdx.x * 192;
  const int lq = lane & 15, g = lane >> 4;
  const int sw = lq & 7;

  f32x4 acc[8][3] = {};
  const int NT = K >> 6;

  auto STAGE_PAIR = [&](int bb, int kt) {
#pragma unroll
    for (int i = 0; i < 4; ++i) {              // A: 2048 chunks, 4/thread
      int ci = tid + i * 512;
      int r = ci >> 3;
      int jl = ((ci & 7) ^ (r & 7)) << 3;      // inverse swizzle on source
      GLOAD16(A + (size_t)(m0 + r) * K + kt + jl, &As[bb][ci * 8]);
    }
#pragma unroll
    for (int i = 0; i < 3; ++i) {              // B: 1536 chunks, 3/thread
      int ci = tid + i * 512;
      int r = ci >> 3;
      int jl = ((ci & 7) ^ (r & 7)) << 3;
      GLOAD16(Bt + (size_t)(n0 + r) * K + kt + jl, &Bs[bb][ci * 8]);
    }
  };

  STAGE_PAIR(0, 0);

  for (int t = 0; t < NT; ++t) {
    const int c = t & 1;
    const bool more = (t + 1) < NT;

    // ---- phase 0 (k 0..31) ----
    asm volatile("s_waitcnt vmcnt(0)" ::: "memory");   // pair(t): issued 2 phases ago
    __builtin_amdgcn_s_barrier();
    bf16x8 af[8], bf[3];
#pragma unroll
    for (int mi = 0; mi < 8; ++mi)
      af[mi] = *(const bf16x8*)&As[c][(wm * 128 + mi * 16 + lq) * 64 + ((g ^ sw) << 3)];
#pragma unroll
    for (int ni = 0; ni < 3; ++ni)
      bf[ni] = *(const bf16x8*)&Bs[c][(wn * 48 + ni * 16 + lq) * 64 + ((g ^ sw) << 3)];
    if (more) STAGE_PAIR(c ^ 1, (t + 1) << 6);
    asm volatile("s_waitcnt lgkmcnt(0)" ::: "memory");
    __builtin_amdgcn_sched_barrier(0);
    __builtin_amdgcn_s_setprio(1);
#pragma unroll
    for (int mi = 0; mi < 8; ++mi)
#pragma unroll
      for (int ni = 0; ni < 3; ++ni)
        acc[mi][ni] = __builtin_amdgcn_mfma_f32_16x16x32_bf16(af[mi], bf[ni], acc[mi][ni], 0, 0, 0);
    __builtin_amdgcn_s_setprio(0);

    // ---- phase 1 (k 32..63): same buffer, no barrier/vmcnt needed ----
#pragma unroll
    for (int mi = 0; mi < 8; ++mi)
      af[mi] = *(const bf16x8*)&As[c][(wm * 128 + mi * 16 + lq) * 64 + (((4 + g) ^ sw) << 3)];
#pragma unroll
    for (int ni = 0; ni < 3; ++ni)
      bf[ni] = *(const bf16x8*)&Bs[c][(wn * 48 + ni * 16 + lq) * 64 + (((4 + g) ^ sw) << 3)];
    asm volatile("s_waitcnt lgkmcnt(0)" ::: "memory");
    __builtin_amdgcn_sched_barrier(0);
    __builtin_amdgcn_s_setprio(1);
#pragma unroll
    for (int mi = 0; mi < 8; ++mi)
#pragma unroll
      for (int ni = 0; ni < 3; ++ni)
        acc[mi][ni] = __builtin_amdgcn_mfma_f32_16x16x32_bf16(af[mi], bf[ni], acc[mi][ni], 0, 0, 0);
    __builtin_amdgcn_s_setprio(0);
  }

  // epilogue
#pragma unroll
  for (int mi = 0; mi < 8; ++mi)
#pragma unroll
    for (int ni = 0; ni < 3; ++ni) {
      int row = m0 + wm * 128 + mi * 16 + g * 4;
      int col = n0 + wn * 48 + ni * 16 + lq;
#pragma unroll
      for (int r = 0; r < 4; ++r)
        storeC(C, (size_t)(row + r) * ldc + col, acc[mi][ni][r]);
    }
}

// ---------------- RoPE (in-place on QKV buffer), scale folded into Q ----------------
__global__ void rope_kernel(unsigned short* __restrict__ qkv) {
  int idx = blockIdx.x * blockDim.x + threadIdx.x;  // S * 40 heads * 64 pairs
  int d = idx & 63;
  int h = (idx >> 6) % (NH + NKV);
  int s = (idx >> 6) / (NH + NKV);
  size_t base = (size_t)s * QKVN + (h < NH ? h * HD : NH * HD + (h - NH) * HD);
  float invf = __expf(-(float)d * (1.0f / 64.0f) * 9.210340371976184f);  // 10000^(-d/64)
  float ang = (float)s * invf;
  float c, sn;
  __sincosf(ang, &sn, &c);
  float x1 = bf2f(qkv[base + d]);
  float x2 = bf2f(qkv[base + d + 64]);
  float o1 = x1 * c - x2 * sn;
  float o2 = x2 * c + x1 * sn;
  if (h < NH) {  // fold 1/sqrt(128) attention scale into Q
    o1 *= 0.08838834764831845f;
    o2 *= 0.08838834764831845f;
  }
  qkv[base + d] = f2bf(o1);
  qkv[base + d + 64] = f2bf(o2);
}

// ---------------- flash attention v11 (r18): late raw barrier B ----------------
__launch_bounds__(512, 4)
__global__ void attn_kernel(const unsigned short* __restrict__ qkv,
                            unsigned short* __restrict__ ao) {
  __shared__ unsigned short Ks[2][64 * 128];   // 32 KB
  __shared__ unsigned short Vt[128 * 88];      // 22 KB
  __shared__ unsigned short Ps[8][16 * 88];    // 22.5 KB  (total 76 KB -> 2 blocks/CU)

  const int tid = threadIdx.x, lane = tid & 63, w = tid >> 6;  // w in 0..7
  const int b = blockIdx.x;          // 0..15
  const int h = blockIdx.y;
  const int qblk = (h < 16) ? (15 - b) : b;   // antisymmetric: CU pair sums constant
  const int kh = h >> 2;
  const int lq = lane & 15, g = lane >> 4;
  const int qbase = qblk * 128 + w * 16;
  const size_t koff = (size_t)NH * HD + (size_t)kh * HD;
  const size_t voff = (size_t)(NH + NKV) * HD + (size_t)kh * HD;

  // Q fragments: qf[ks] = Q[qbase+lq][ks*32 + g*8 ..+8]
  bf16x8 qf[4];
  {
    const unsigned short* qp = qkv + (size_t)(qbase + lq) * QKVN + (size_t)h * HD + g * 8;
#pragma unroll
    for (int ks = 0; ks < 4; ++ks) qf[ks] = *(const bf16x8*)(qp + ks * 32);
  }

  f32x4 o[8] = {};
  float m = -1e30f;   // running max for q = qbase+lq
  float l = 0.f;      // running denom for q = qbase+lq

  // K staging: 8 waves x 2 insts; inst (w,i) covers rows (w*2+i)*4 + (lane>>4)
  auto KSTAGE = [&](int bb, int kv0) {
#pragma unroll
    for (int i = 0; i < 2; ++i) {
      int kvk = (w * 2 + i) * 4 + (lane >> 4);
      int chl = (lane & 15) ^ (kvk & 7);
      GLOAD16(qkv + (size_t)(kv0 + kvk) * QKVN + koff + chl * 8, &Ks[bb][(w * 2 + i) * 512]);
    }
  };
  // V staging by ALL 512 threads: thread covers d = vd0..vd0+3, kv = vkv..vkv+3
  const int vd0 = (tid & 31) * 4;
  const int vkv = (tid >> 5) * 4;
  u16x4 vr[4];
  auto VLOAD = [&](int kv0) {
#pragma unroll
    for (int i = 0; i < 4; ++i)
      vr[i] = *(const u16x4*)(qkv + (size_t)(kv0 + vkv + i) * QKVN + voff + vd0);
  };
  auto VWRITE = [&]() {
#pragma unroll
    for (int j = 0; j < 4; ++j) {
      const int d = vd0 + j;
      const int vswz = ((d >> 3) & 3) << 1;
      const int vcol = (((vkv >> 2) ^ vswz) << 2);
      u16x4 val = {vr[0][j], vr[1][j], vr[2][j], vr[3][j]};
      *(u16x4*)&Vt[d * 88 + vcol] = val;
    }
  };

  unsigned short* Pw = &Ps[w][0];
  const int nt = qblk * 2 + 2;   // tiles to cover rows up to qblk*128+127

  KSTAGE(0, 0);
  VLOAD(0);
  int cur = 0;
  for (int t = 0; t < nt; ++t) {
    const int kv0 = t * 64;
    __syncthreads();                    // A: K(t)/V(t) drained; prev Vt/Ks reads done
    VWRITE();
    if (t + 1 < nt) { KSTAGE(cur ^ 1, kv0 + 64); VLOAD(kv0 + 64); }

    const int nraw = qbase + 16 - kv0;            // may be <= 0 for some waves at last tile
    const int nact = nraw > 64 ? 64 : nraw;

    // ---- QK^T (swapped: sc[st][r] = S[kv=kv0+st*16+g*4+r][q=qbase+lq]) ----
    f32x4 sc[4];
    __builtin_amdgcn_s_setprio(1);
#pragma unroll
    for (int st = 0; st < 4; ++st) {
      if (st * 16 < nact) {
        f32x4 s = {};
#pragma unroll
        for (int ks = 0; ks < 4; ++ks) {
          const bf16x8 kf = *(const bf16x8*)
              &Ks[cur][(st * 16 + lq) * 128 + (((ks * 4 + g) ^ (lq & 7)) << 3)];
          s = __builtin_amdgcn_mfma_f32_16x16x32_bf16(kf, qf[ks], s, 0, 0, 0);
        }
        sc[st] = s;
      } else {
        sc[st] = (f32x4){-1e30f, -1e30f, -1e30f, -1e30f};
      }
    }
    __builtin_amdgcn_s_setprio(0);
    if (nraw < 79) {  // diagonal tile (or dead tile: fully masked, p->0 since m>-1e30)
      const int q = qbase + lq;
#pragma unroll
      for (int st = 0; st < 4; ++st) {
        int kv = kv0 + st * 16 + g * 4;
#pragma unroll
        for (int r = 0; r < 4; ++r)
          if (kv + r > q) sc[st][r] = -1e30f;
      }
    }

    // ---- online softmax: lane-local over 16 values, then 2 shfl rounds over g ----
    float mn = fmaxf(fmaxf(fmaxf(sc[0][0], sc[0][1]), fmaxf(sc[0][2], sc[0][3])),
                     fmaxf(fmaxf(sc[1][0], sc[1][1]), fmaxf(sc[1][2], sc[1][3])));
    mn = fmaxf(mn, fmaxf(fmaxf(fmaxf(sc[2][0], sc[2][1]), fmaxf(sc[2][2], sc[2][3])),
                         fmaxf(fmaxf(sc[3][0], sc[3][1]), fmaxf(sc[3][2], sc[3][3]))));
    mn = fmaxf(mn, __shfl_xor(mn, 16, 64));
    mn = fmaxf(mn, __shfl_xor(mn, 32, 64));
    const bool need = __any(mn > m);   // wave-uniform: does any lane grow its max?
    const float m2 = fmaxf(m, mn);
    const float alpha = __expf(m - m2);  // == 1.0 exactly when !need
    m = m2;
    float rs = 0.f;
#pragma unroll
    for (int st = 0; st < 4; ++st)
#pragma unroll
      for (int r = 0; r < 4; ++r) {
        float p = __expf(sc[st][r] - m2);
        sc[st][r] = p;
        rs += p;
      }
    rs += __shfl_xor(rs, 16, 64);
    rs += __shfl_xor(rs, 32, 64);
    l = l * alpha + rs;

    if (need) {  // T13: skip O-rescale when alpha==1 for all lanes (exact)
      float alphaR[4];
#pragma unroll
      for (int r = 0; r < 4; ++r) alphaR[r] = __shfl(alpha, g * 4 + r, 64);
#pragma unroll
      for (int p = 0; p < 8; ++p)
#pragma unroll
        for (int r = 0; r < 4; ++r) o[p][r] *= alphaR[r];
    }

    // ---- B: Vt(t) visible; raw barrier, NO vmcnt drain (prefetch stays in flight) ----
    asm volatile("s_waitcnt lgkmcnt(0)" ::: "memory");
    __builtin_amdgcn_s_barrier();
    __builtin_amdgcn_sched_barrier(0);

    // ---- P -> LDS via v_cvt_pk_bf16_f32 (RNE, 2 f32/inst) ----
#pragma unroll
    for (int st = 0; st < 4; ++st) {
      unsigned r01, r23;
      asm("v_cvt_pk_bf16_f32 %0, %1, %2" : "=v"(r01) : "v"(sc[st][0]), "v"(sc[st][1]));
      asm("v_cvt_pk_bf16_f32 %0, %1, %2" : "=v"(r23) : "v"(sc[st][2]), "v"(sc[st][3]));
      unsigned* dst = (unsigned*)&Pw[lq * 88 + st * 16 + g * 4];
      dst[0] = r01; dst[1] = r23;
    }

    // ---- O += P V ----
    const int nks = nact > 0 ? (nact + 31) >> 5 : 0;
    __builtin_amdgcn_s_setprio(1);
    for (int ks = 0; ks < nks; ++ks) {
      const bf16x8 pf = *(const bf16x8*)&Pw[lq * 88 + ks * 32 + g * 8];
#pragma unroll
      for (int p = 0; p < 8; ++p) {
        const int d = p * 16 + lq;
        const int rswz = ((d >> 3) & 3) << 1;
        const int kvc = (ks * 8 + g * 2) ^ rswz;
        const bf16x8 vf = *(const bf16x8*)&Vt[d * 88 + (kvc << 2)];
        o[p] = __builtin_amdgcn_mfma_f32_16x16x32_bf16(pf, vf, o[p], 0, 0, 0);
      }
    }
    __builtin_amdgcn_s_setprio(0);

    cur ^= 1;
  }

  // epilogue: O / l -> ao (bf16, [s][NH*HD]); l for row g*4+r from lane lq=g*4+r
  float invR[4];
#pragma unroll
  for (int r = 0; r < 4; ++r) invR[r] = 1.0f / __shfl(l, g * 4 + r, 64);
#pragma unroll
  for (int p = 0; p < 8; ++p)
#pragma unroll
    for (int r = 0; r < 4; ++r)
      ao[(size_t)(qbase + g * 4 + r) * (NH * HD) + (size_t)h * HD + p * 16 + lq] =
          f2bf(o[p][r] * invR[r]);
}

extern "C" void kernel_launch(void* const* d_in, const int* in_sizes, int n_in,
                              void* d_out, int out_size, void* d_ws, size_t ws_size,
                              hipStream_t stream) {
  const float* X  = (const float*)d_in[0];
  const float* qw = (const float*)d_in[2];
  const float* kw = (const float*)d_in[3];
  const float* vw = (const float*)d_in[4];
  const float* ow = (const float*)d_in[5];
  float* out = (float*)d_out;

  char* ws = (char*)d_ws;
  unsigned short* Xb  = (unsigned short*)(ws);
  unsigned short* Wt  = (unsigned short*)(ws + (size_t)(16u << 20));
  unsigned short* QKV = (unsigned short*)(ws + (size_t)(64u << 20));
  unsigned short* AO  = (unsigned short*)(ws + (size_t)(88u << 20));
  unsigned short* OWt = (unsigned short*)(ws);

  dim3 tb(32, 8);

  convert_kernel<<<(S * HID / 4 + 255) / 256, 256, 0, stream>>>(X, Xb, S * HID / 4);
  transpose_qkv<<<dim3(QKVN / 32, HID / 32), tb, 0, stream>>>(qw, kw, vw, Wt);
  gemm_qkv<unsigned short><<<dim3(QKVN / 192, S / 256), 512, 0, stream>>>(Xb, Wt, QKV, HID, QKVN);
  transpose_convert<<<dim3(HID / 32, HID / 32), tb, 0, stream>>>(ow, OWt, HID);
  rope_kernel<<<(S * (NH + NKV) * 64) / 256, 256, 0, stream>>>(QKV);
  attn_kernel<<<dim3(16, NH), 512, 0, stream>>>(QKV, AO);
  // out = AO @ OWt^T : 256x128 8-wave v2, grid 32x8 = 256 blocks = exact fill
  gemm_o<float><<<dim3(HID / 128, S / 256), 512, 0, stream>>>(AO, OWt, out, HID, HID);
}

// Round 20
// 306.454 us; speedup vs baseline: 1.0225x; 1.0225x over previous
//
#include <hip/hip_runtime.h>
#include <hip/hip_bf16.h>

#define S 2048
#define HID 4096
#define NH 32
#define NKV 8
#define HD 128
#define QKVN 6144  // NH*HD + 2*NKV*HD

typedef __attribute__((ext_vector_type(8))) short bf16x8;
typedef __attribute__((ext_vector_type(4))) float f32x4;
typedef __attribute__((ext_vector_type(8))) unsigned short u16x8;
typedef __attribute__((ext_vector_type(4))) unsigned short u16x4;

#define GLOAD16(src, dst)                                                        \
  __builtin_amdgcn_global_load_lds(                                              \
      (const __attribute__((address_space(1))) unsigned int*)(src),              \
      (__attribute__((address_space(3))) unsigned int*)(dst), 16, 0, 0)

__device__ __forceinline__ unsigned short f2bf(float f) {
  union { float f; unsigned u; } c; c.f = f;
  unsigned u = c.u;
  return (unsigned short)((u + 0x7FFFu + ((u >> 16) & 1u)) >> 16);
}
__device__ __forceinline__ float bf2f(unsigned short h) {
  union { unsigned u; float f; } c; c.u = ((unsigned)h) << 16;
  return c.f;
}

// ---------------- fp32 -> bf16 convert (vector4) ----------------
__global__ void convert_kernel(const float* __restrict__ in,
                               unsigned short* __restrict__ out, int n4) {
  int i = blockIdx.x * blockDim.x + threadIdx.x;
  if (i < n4) {
    float4 v = ((const float4*)in)[i];
    ushort4 o;
    o.x = f2bf(v.x); o.y = f2bf(v.y); o.z = f2bf(v.z); o.w = f2bf(v.w);
    ((ushort4*)out)[i] = o;
  }
}

// ---------------- merged q/k/v weight transpose+convert -> Wt rows [0,6144) ----------------
__global__ void transpose_qkv(const float* __restrict__ qw,
                              const float* __restrict__ kw,
                              const float* __restrict__ vw,
                              unsigned short* __restrict__ out) {
  __shared__ float tile[32][33];
  int tx = threadIdx.x, ty = threadIdx.y;       // 32 x 8
  int n0 = blockIdx.x * 32, k0 = blockIdx.y * 32;
  const float* in;
  int N, nn;
  if (n0 < NH * HD)                 { in = qw; N = NH * HD;  nn = n0; }
  else if (n0 < (NH + NKV) * HD)    { in = kw; N = NKV * HD; nn = n0 - NH * HD; }
  else                              { in = vw; N = NKV * HD; nn = n0 - (NH + NKV) * HD; }
#pragma unroll
  for (int i = 0; i < 32; i += 8)
    tile[ty + i][tx] = in[(size_t)(k0 + ty + i) * N + nn + tx];
  __syncthreads();
#pragma unroll
  for (int i = 0; i < 32; i += 8)
    out[(size_t)(n0 + ty + i) * HID + k0 + tx] = f2bf(tile[tx][ty + i]);
}

// ---------------- transpose + convert: in [K][N] f32 -> out [N][K=4096] bf16 ----------------
__global__ void transpose_convert(const float* __restrict__ in,
                                  unsigned short* __restrict__ out, int N) {
  __shared__ float tile[32][33];
  int tx = threadIdx.x, ty = threadIdx.y;       // 32 x 8
  int n0 = blockIdx.x * 32, k0 = blockIdx.y * 32;
#pragma unroll
  for (int i = 0; i < 32; i += 8)
    tile[ty + i][tx] = in[(size_t)(k0 + ty + i) * N + n0 + tx];
  __syncthreads();
#pragma unroll
  for (int i = 0; i < 32; i += 8)
    out[(size_t)(n0 + ty + i) * HID + k0 + tx] = f2bf(tile[tx][ty + i]);
}

__device__ __forceinline__ void storeC(unsigned short* C, size_t idx, float v) { C[idx] = f2bf(v); }
__device__ __forceinline__ void storeC(float* C, size_t idx, float v) { C[idx] = v; }

// ---------------- bf16 GEMM 128^2 v2 (r16-proven): O-projection (2 blocks/CU) ----------------
template <typename OutT>
__launch_bounds__(256, 2)
__global__ void gemm_bt(const unsigned short* __restrict__ A,
                        const unsigned short* __restrict__ Bt,
                        OutT* __restrict__ C, int K, int ldc) {
  __shared__ unsigned short As[2][128 * 64];   // 32 KB
  __shared__ unsigned short Bs[2][128 * 64];   // 32 KB
  const int tid = threadIdx.x, lane = tid & 63, w = tid >> 6;
  const int wr = w >> 1, wc = w & 1;
  const int m0 = blockIdx.y * 128, n0 = blockIdx.x * 128;
  const int lq = lane & 15, g = lane >> 4;
  const int sw = lq & 7;

  f32x4 acc[4][4] = {};
  const int NT = K >> 6;

  auto STAGE_PAIR = [&](int bb, int kt) {
#pragma unroll
    for (int i = 0; i < 4; ++i) {
      int ci = tid + i * 256;                  // chunk id in [0,1024)
      int r = ci >> 3;
      int jl = ((ci & 7) ^ (r & 7)) << 3;      // inverse swizzle on source
      GLOAD16(A + (size_t)(m0 + r) * K + kt + jl, &As[bb][ci * 8]);
      GLOAD16(Bt + (size_t)(n0 + r) * K + kt + jl, &Bs[bb][ci * 8]);
    }
  };

  STAGE_PAIR(0, 0);

  for (int t = 0; t < NT; ++t) {
    const int c = t & 1;
    const bool more = (t + 1) < NT;

    // ---- phase 0 (k 0..31) ----
    asm volatile("s_waitcnt vmcnt(0)" ::: "memory");   // pair(t): issued 2 phases ago
    __builtin_amdgcn_s_barrier();
    bf16x8 af[4], bf[4];
#pragma unroll
    for (int mi = 0; mi < 4; ++mi)
      af[mi] = *(const bf16x8*)&As[c][(wr * 64 + mi * 16 + lq) * 64 + ((g ^ sw) << 3)];
#pragma unroll
    for (int ni = 0; ni < 4; ++ni)
      bf[ni] = *(const bf16x8*)&Bs[c][(wc * 64 + ni * 16 + lq) * 64 + ((g ^ sw) << 3)];
    if (more) STAGE_PAIR(c ^ 1, (t + 1) << 6);
    asm volatile("s_waitcnt lgkmcnt(0)" ::: "memory");
    __builtin_amdgcn_sched_barrier(0);
    __builtin_amdgcn_s_setprio(1);
#pragma unroll
    for (int mi = 0; mi < 4; ++mi)
#pragma unroll
      for (int ni = 0; ni < 4; ++ni)
        acc[mi][ni] = __builtin_amdgcn_mfma_f32_16x16x32_bf16(af[mi], bf[ni], acc[mi][ni], 0, 0, 0);
    __builtin_amdgcn_s_setprio(0);

    // ---- phase 1 (k 32..63): same buffer, no barrier/vmcnt needed ----
#pragma unroll
    for (int mi = 0; mi < 4; ++mi)
      af[mi] = *(const bf16x8*)&As[c][(wr * 64 + mi * 16 + lq) * 64 + (((4 + g) ^ sw) << 3)];
#pragma unroll
    for (int ni = 0; ni < 4; ++ni)
      bf[ni] = *(const bf16x8*)&Bs[c][(wc * 64 + ni * 16 + lq) * 64 + (((4 + g) ^ sw) << 3)];
    asm volatile("s_waitcnt lgkmcnt(0)" ::: "memory");
    __builtin_amdgcn_sched_barrier(0);
    __builtin_amdgcn_s_setprio(1);
#pragma unroll
    for (int mi = 0; mi < 4; ++mi)
#pragma unroll
      for (int ni = 0; ni < 4; ++ni)
        acc[mi][ni] = __builtin_amdgcn_mfma_f32_16x16x32_bf16(af[mi], bf[ni], acc[mi][ni], 0, 0, 0);
    __builtin_amdgcn_s_setprio(0);
  }

  // epilogue (r3-proven indices)
#pragma unroll
  for (int mi = 0; mi < 4; ++mi) {
#pragma unroll
    for (int ni = 0; ni < 4; ++ni) {
      int row = m0 + wr * 64 + mi * 16 + g * 4;
      int col = n0 + wc * 64 + ni * 16 + lq;
#pragma unroll
      for (int r = 0; r < 4; ++r)
        storeC(C, (size_t)(row + r) * ldc + col, acc[mi][ni][r]);
    }
  }
}

// ---------------- bf16 GEMM 256x192 (r17-proven, 97us): QKV projection ----------------
template <typename OutT>
__launch_bounds__(512, 1)
__global__ void gemm_qkv(const unsigned short* __restrict__ A,
                         const unsigned short* __restrict__ Bt,
                         OutT* __restrict__ C, int K, int ldc) {
  __shared__ unsigned short As[2][256 * 64];   // 64 KB
  __shared__ unsigned short Bs[2][192 * 64];   // 48 KB
  const int tid = threadIdx.x, lane = tid & 63, w = tid >> 6;
  const int wm = w >> 2, wn = w & 3;           // 2M x 4N wave grid
  const int m0 = blockIdx.y * 256, n0 = blockIdx.x * 192;
  const int lq = lane & 15, g = lane >> 4;
  const int sw = lq & 7;

  f32x4 acc[8][3] = {};
  const int NT = K >> 6;

  auto STAGE_PAIR = [&](int bb, int kt) {
#pragma unroll
    for (int i = 0; i < 4; ++i) {              // A: 2048 chunks, 4/thread
      int ci = tid + i * 512;
      int r = ci >> 3;
      int jl = ((ci & 7) ^ (r & 7)) << 3;      // inverse swizzle on source
      GLOAD16(A + (size_t)(m0 + r) * K + kt + jl, &As[bb][ci * 8]);
    }
#pragma unroll
    for (int i = 0; i < 3; ++i) {              // B: 1536 chunks, 3/thread
      int ci = tid + i * 512;
      int r = ci >> 3;
      int jl = ((ci & 7) ^ (r & 7)) << 3;
      GLOAD16(Bt + (size_t)(n0 + r) * K + kt + jl, &Bs[bb][ci * 8]);
    }
  };

  STAGE_PAIR(0, 0);

  for (int t = 0; t < NT; ++t) {
    const int c = t & 1;
    const bool more = (t + 1) < NT;

    // ---- phase 0 (k 0..31) ----
    asm volatile("s_waitcnt vmcnt(0)" ::: "memory");   // pair(t): issued 2 phases ago
    __builtin_amdgcn_s_barrier();
    bf16x8 af[8], bf[3];
#pragma unroll
    for (int mi = 0; mi < 8; ++mi)
      af[mi] = *(const bf16x8*)&As[c][(wm * 128 + mi * 16 + lq) * 64 + ((g ^ sw) << 3)];
#pragma unroll
    for (int ni = 0; ni < 3; ++ni)
      bf[ni] = *(const bf16x8*)&Bs[c][(wn * 48 + ni * 16 + lq) * 64 + ((g ^ sw) << 3)];
    if (more) STAGE_PAIR(c ^ 1, (t + 1) << 6);
    asm volatile("s_waitcnt lgkmcnt(0)" ::: "memory");
    __builtin_amdgcn_sched_barrier(0);
    __builtin_amdgcn_s_setprio(1);
#pragma unroll
    for (int mi = 0; mi < 8; ++mi)
#pragma unroll
      for (int ni = 0; ni < 3; ++ni)
        acc[mi][ni] = __builtin_amdgcn_mfma_f32_16x16x32_bf16(af[mi], bf[ni], acc[mi][ni], 0, 0, 0);
    __builtin_amdgcn_s_setprio(0);

    // ---- phase 1 (k 32..63): same buffer, no barrier/vmcnt needed ----
#pragma unroll
    for (int mi = 0; mi < 8; ++mi)
      af[mi] = *(const bf16x8*)&As[c][(wm * 128 + mi * 16 + lq) * 64 + (((4 + g) ^ sw) << 3)];
#pragma unroll
    for (int ni = 0; ni < 3; ++ni)
      bf[ni] = *(const bf16x8*)&Bs[c][(wn * 48 + ni * 16 + lq) * 64 + (((4 + g) ^ sw) << 3)];
    asm volatile("s_waitcnt lgkmcnt(0)" ::: "memory");
    __builtin_amdgcn_sched_barrier(0);
    __builtin_amdgcn_s_setprio(1);
#pragma unroll
    for (int mi = 0; mi < 8; ++mi)
#pragma unroll
      for (int ni = 0; ni < 3; ++ni)
        acc[mi][ni] = __builtin_amdgcn_mfma_f32_16x16x32_bf16(af[mi], bf[ni], acc[mi][ni], 0, 0, 0);
    __builtin_amdgcn_s_setprio(0);
  }

  // epilogue
#pragma unroll
  for (int mi = 0; mi < 8; ++mi)
#pragma unroll
    for (int ni = 0; ni < 3; ++ni) {
      int row = m0 + wm * 128 + mi * 16 + g * 4;
      int col = n0 + wn * 48 + ni * 16 + lq;
#pragma unroll
      for (int r = 0; r < 4; ++r)
        storeC(C, (size_t)(row + r) * ldc + col, acc[mi][ni][r]);
    }
}

// ---------------- RoPE (in-place on QKV buffer), scale folded into Q ----------------
__global__ void rope_kernel(unsigned short* __restrict__ qkv) {
  int idx = blockIdx.x * blockDim.x + threadIdx.x;  // S * 40 heads * 64 pairs
  int d = idx & 63;
  int h = (idx >> 6) % (NH + NKV);
  int s = (idx >> 6) / (NH + NKV);
  size_t base = (size_t)s * QKVN + (h < NH ? h * HD : NH * HD + (h - NH) * HD);
  float invf = __expf(-(float)d * (1.0f / 64.0f) * 9.210340371976184f);  // 10000^(-d/64)
  float ang = (float)s * invf;
  float c, sn;
  __sincosf(ang, &sn, &c);
  float x1 = bf2f(qkv[base + d]);
  float x2 = bf2f(qkv[base + d + 64]);
  float o1 = x1 * c - x2 * sn;
  float o2 = x2 * c + x1 * sn;
  if (h < NH) {  // fold 1/sqrt(128) attention scale into Q
    o1 *= 0.08838834764831845f;
    o2 *= 0.08838834764831845f;
  }
  qkv[base + d] = f2bf(o1);
  qkv[base + d + 64] = f2bf(o2);
}

// ---------------- flash attention v11 (r18-proven): late raw barrier B ----------------
__launch_bounds__(512, 4)
__global__ void attn_kernel(const unsigned short* __restrict__ qkv,
                            unsigned short* __restrict__ ao) {
  __shared__ unsigned short Ks[2][64 * 128];   // 32 KB
  __shared__ unsigned short Vt[128 * 88];      // 22 KB
  __shared__ unsigned short Ps[8][16 * 88];    // 22.5 KB  (total 76 KB -> 2 blocks/CU)

  const int tid = threadIdx.x, lane = tid & 63, w = tid >> 6;  // w in 0..7
  const int b = blockIdx.x;          // 0..15
  const int h = blockIdx.y;
  const int qblk = (h < 16) ? (15 - b) : b;   // antisymmetric: CU pair sums constant
  const int kh = h >> 2;
  const int lq = lane & 15, g = lane >> 4;
  const int qbase = qblk * 128 + w * 16;
  const size_t koff = (size_t)NH * HD + (size_t)kh * HD;
  const size_t voff = (size_t)(NH + NKV) * HD + (size_t)kh * HD;

  // Q fragments: qf[ks] = Q[qbase+lq][ks*32 + g*8 ..+8]
  bf16x8 qf[4];
  {
    const unsigned short* qp = qkv + (size_t)(qbase + lq) * QKVN + (size_t)h * HD + g * 8;
#pragma unroll
    for (int ks = 0; ks < 4; ++ks) qf[ks] = *(const bf16x8*)(qp + ks * 32);
  }

  f32x4 o[8] = {};
  float m = -1e30f;   // running max for q = qbase+lq
  float l = 0.f;      // running denom for q = qbase+lq

  // K staging: 8 waves x 2 insts; inst (w,i) covers rows (w*2+i)*4 + (lane>>4)
  auto KSTAGE = [&](int bb, int kv0) {
#pragma unroll
    for (int i = 0; i < 2; ++i) {
      int kvk = (w * 2 + i) * 4 + (lane >> 4);
      int chl = (lane & 15) ^ (kvk & 7);
      GLOAD16(qkv + (size_t)(kv0 + kvk) * QKVN + koff + chl * 8, &Ks[bb][(w * 2 + i) * 512]);
    }
  };
  // V staging by ALL 512 threads: thread covers d = vd0..vd0+3, kv = vkv..vkv+3
  const int vd0 = (tid & 31) * 4;
  const int vkv = (tid >> 5) * 4;
  u16x4 vr[4];
  auto VLOAD = [&](int kv0) {
#pragma unroll
    for (int i = 0; i < 4; ++i)
      vr[i] = *(const u16x4*)(qkv + (size_t)(kv0 + vkv + i) * QKVN + voff + vd0);
  };
  auto VWRITE = [&]() {
#pragma unroll
    for (int j = 0; j < 4; ++j) {
      const int d = vd0 + j;
      const int vswz = ((d >> 3) & 3) << 1;
      const int vcol = (((vkv >> 2) ^ vswz) << 2);
      u16x4 val = {vr[0][j], vr[1][j], vr[2][j], vr[3][j]};
      *(u16x4*)&Vt[d * 88 + vcol] = val;
    }
  };

  unsigned short* Pw = &Ps[w][0];
  const int nt = qblk * 2 + 2;   // tiles to cover rows up to qblk*128+127

  KSTAGE(0, 0);
  VLOAD(0);
  int cur = 0;
  for (int t = 0; t < nt; ++t) {
    const int kv0 = t * 64;
    __syncthreads();                    // A: K(t)/V(t) drained; prev Vt/Ks reads done
    VWRITE();
    if (t + 1 < nt) { KSTAGE(cur ^ 1, kv0 + 64); VLOAD(kv0 + 64); }

    const int nraw = qbase + 16 - kv0;            // may be <= 0 for some waves at last tile
    const int nact = nraw > 64 ? 64 : nraw;

    // ---- QK^T (swapped: sc[st][r] = S[kv=kv0+st*16+g*4+r][q=qbase+lq]) ----
    f32x4 sc[4];
    __builtin_amdgcn_s_setprio(1);
#pragma unroll
    for (int st = 0; st < 4; ++st) {
      if (st * 16 < nact) {
        f32x4 s = {};
#pragma unroll
        for (int ks = 0; ks < 4; ++ks) {
          const bf16x8 kf = *(const bf16x8*)
              &Ks[cur][(st * 16 + lq) * 128 + (((ks * 4 + g) ^ (lq & 7)) << 3)];
          s = __builtin_amdgcn_mfma_f32_16x16x32_bf16(kf, qf[ks], s, 0, 0, 0);
        }
        sc[st] = s;
      } else {
        sc[st] = (f32x4){-1e30f, -1e30f, -1e30f, -1e30f};
      }
    }
    __builtin_amdgcn_s_setprio(0);
    if (nraw < 79) {  // diagonal tile (or dead tile: fully masked, p->0 since m>-1e30)
      const int q = qbase + lq;
#pragma unroll
      for (int st = 0; st < 4; ++st) {
        int kv = kv0 + st * 16 + g * 4;
#pragma unroll
        for (int r = 0; r < 4; ++r)
          if (kv + r > q) sc[st][r] = -1e30f;
      }
    }

    // ---- online softmax: lane-local over 16 values, then 2 shfl rounds over g ----
    float mn = fmaxf(fmaxf(fmaxf(sc[0][0], sc[0][1]), fmaxf(sc[0][2], sc[0][3])),
                     fmaxf(fmaxf(sc[1][0], sc[1][1]), fmaxf(sc[1][2], sc[1][3])));
    mn = fmaxf(mn, fmaxf(fmaxf(fmaxf(sc[2][0], sc[2][1]), fmaxf(sc[2][2], sc[2][3])),
                         fmaxf(fmaxf(sc[3][0], sc[3][1]), fmaxf(sc[3][2], sc[3][3]))));
    mn = fmaxf(mn, __shfl_xor(mn, 16, 64));
    mn = fmaxf(mn, __shfl_xor(mn, 32, 64));
    const bool need = __any(mn > m);   // wave-uniform: does any lane grow its max?
    const float m2 = fmaxf(m, mn);
    const float alpha = __expf(m - m2);  // == 1.0 exactly when !need
    m = m2;
    float rs = 0.f;
#pragma unroll
    for (int st = 0; st < 4; ++st)
#pragma unroll
      for (int r = 0; r < 4; ++r) {
        float p = __expf(sc[st][r] - m2);
        sc[st][r] = p;
        rs += p;
      }
    rs += __shfl_xor(rs, 16, 64);
    rs += __shfl_xor(rs, 32, 64);
    l = l * alpha + rs;

    if (need) {  // T13: skip O-rescale when alpha==1 for all lanes (exact)
      float alphaR[4];
#pragma unroll
      for (int r = 0; r < 4; ++r) alphaR[r] = __shfl(alpha, g * 4 + r, 64);
#pragma unroll
      for (int p = 0; p < 8; ++p)
#pragma unroll
        for (int r = 0; r < 4; ++r) o[p][r] *= alphaR[r];
    }

    // ---- B: Vt(t) visible; raw barrier, NO vmcnt drain (prefetch stays in flight) ----
    asm volatile("s_waitcnt lgkmcnt(0)" ::: "memory");
    __builtin_amdgcn_s_barrier();
    __builtin_amdgcn_sched_barrier(0);

    // ---- P -> LDS via v_cvt_pk_bf16_f32 (RNE, 2 f32/inst) ----
#pragma unroll
    for (int st = 0; st < 4; ++st) {
      unsigned r01, r23;
      asm("v_cvt_pk_bf16_f32 %0, %1, %2" : "=v"(r01) : "v"(sc[st][0]), "v"(sc[st][1]));
      asm("v_cvt_pk_bf16_f32 %0, %1, %2" : "=v"(r23) : "v"(sc[st][2]), "v"(sc[st][3]));
      unsigned* dst = (unsigned*)&Pw[lq * 88 + st * 16 + g * 4];
      dst[0] = r01; dst[1] = r23;
    }

    // ---- O += P V ----
    const int nks = nact > 0 ? (nact + 31) >> 5 : 0;
    __builtin_amdgcn_s_setprio(1);
    for (int ks = 0; ks < nks; ++ks) {
      const bf16x8 pf = *(const bf16x8*)&Pw[lq * 88 + ks * 32 + g * 8];
#pragma unroll
      for (int p = 0; p < 8; ++p) {
        const int d = p * 16 + lq;
        const int rswz = ((d >> 3) & 3) << 1;
        const int kvc = (ks * 8 + g * 2) ^ rswz;
        const bf16x8 vf = *(const bf16x8*)&Vt[d * 88 + (kvc << 2)];
        o[p] = __builtin_amdgcn_mfma_f32_16x16x32_bf16(pf, vf, o[p], 0, 0, 0);
      }
    }
    __builtin_amdgcn_s_setprio(0);

    cur ^= 1;
  }

  // epilogue: O / l -> ao (bf16, [s][NH*HD]); l for row g*4+r from lane lq=g*4+r
  float invR[4];
#pragma unroll
  for (int r = 0; r < 4; ++r) invR[r] = 1.0f / __shfl(l, g * 4 + r, 64);
#pragma unroll
  for (int p = 0; p < 8; ++p)
#pragma unroll
    for (int r = 0; r < 4; ++r)
      ao[(size_t)(qbase + g * 4 + r) * (NH * HD) + (size_t)h * HD + p * 16 + lq] =
          f2bf(o[p][r] * invR[r]);
}

extern "C" void kernel_launch(void* const* d_in, const int* in_sizes, int n_in,
                              void* d_out, int out_size, void* d_ws, size_t ws_size,
                              hipStream_t stream) {
  const float* X  = (const float*)d_in[0];
  const float* qw = (const float*)d_in[2];
  const float* kw = (const float*)d_in[3];
  const float* vw = (const float*)d_in[4];
  const float* ow = (const float*)d_in[5];
  float* out = (float*)d_out;

  char* ws = (char*)d_ws;
  unsigned short* Xb  = (unsigned short*)(ws);
  unsigned short* Wt  = (unsigned short*)(ws + (size_t)(16u << 20));
  unsigned short* QKV = (unsigned short*)(ws + (size_t)(64u << 20));
  unsigned short* AO  = (unsigned short*)(ws + (size_t)(88u << 20));
  unsigned short* OWt = (unsigned short*)(ws);

  dim3 tb(32, 8);

  convert_kernel<<<(S * HID / 4 + 255) / 256, 256, 0, stream>>>(X, Xb, S * HID / 4);
  transpose_qkv<<<dim3(QKVN / 32, HID / 32), tb, 0, stream>>>(qw, kw, vw, Wt);
  gemm_qkv<unsigned short><<<dim3(QKVN / 192, S / 256), 512, 0, stream>>>(Xb, Wt, QKV, HID, QKVN);
  transpose_convert<<<dim3(HID / 32, HID / 32), tb, 0, stream>>>(ow, OWt, HID);
  rope_kernel<<<(S * (NH + NKV) * 64) / 256, 256, 0, stream>>>(QKV);
  attn_kernel<<<dim3(16, NH), 512, 0, stream>>>(QKV, AO);
  // out = AO @ OWt^T : 128^2 v2 (r16-proven), grid 32x16 = 512 blocks (2/CU)
  gemm_bt<float><<<dim3(HID / 128, S / 128), 256, 0, stream>>>(AO, OWt, out, HID, HID);
}

// Round 21
// 299.716 us; speedup vs baseline: 1.0455x; 1.0225x over previous
//
#include <hip/hip_runtime.h>
#include <hip/hip_bf16.h>

#define S 2048
#define HID 4096
#define NH 32
#define NKV 8
#define HD 128
#define QKVN 6144  // NH*HD + 2*NKV*HD

typedef __attribute__((ext_vector_type(8))) short bf16x8;
typedef __attribute__((ext_vector_type(4))) float f32x4;
typedef __attribute__((ext_vector_type(8))) unsigned short u16x8;
typedef __attribute__((ext_vector_type(4))) unsigned short u16x4;

#define GLOAD16(src, dst)                                                        \
  __builtin_amdgcn_global_load_lds(                                              \
      (const __attribute__((address_space(1))) unsigned int*)(src),              \
      (__attribute__((address_space(3))) unsigned int*)(dst), 16, 0, 0)

__device__ __forceinline__ unsigned short f2bf(float f) {
  union { float f; unsigned u; } c; c.f = f;
  unsigned u = c.u;
  return (unsigned short)((u + 0x7FFFu + ((u >> 16) & 1u)) >> 16);
}
__device__ __forceinline__ float bf2f(unsigned short h) {
  union { unsigned u; float f; } c; c.u = ((unsigned)h) << 16;
  return c.f;
}

// ---------------- fp32 -> bf16 convert (vector4) ----------------
__global__ void convert_kernel(const float* __restrict__ in,
                               unsigned short* __restrict__ out, int n4) {
  int i = blockIdx.x * blockDim.x + threadIdx.x;
  if (i < n4) {
    float4 v = ((const float4*)in)[i];
    ushort4 o;
    o.x = f2bf(v.x); o.y = f2bf(v.y); o.z = f2bf(v.z); o.w = f2bf(v.w);
    ((ushort4*)out)[i] = o;
  }
}

// ---------------- merged q/k/v weight transpose+convert -> Wt rows [0,6144) ----------------
__global__ void transpose_qkv(const float* __restrict__ qw,
                              const float* __restrict__ kw,
                              const float* __restrict__ vw,
                              unsigned short* __restrict__ out) {
  __shared__ float tile[32][33];
  int tx = threadIdx.x, ty = threadIdx.y;       // 32 x 8
  int n0 = blockIdx.x * 32, k0 = blockIdx.y * 32;
  const float* in;
  int N, nn;
  if (n0 < NH * HD)                 { in = qw; N = NH * HD;  nn = n0; }
  else if (n0 < (NH + NKV) * HD)    { in = kw; N = NKV * HD; nn = n0 - NH * HD; }
  else                              { in = vw; N = NKV * HD; nn = n0 - (NH + NKV) * HD; }
#pragma unroll
  for (int i = 0; i < 32; i += 8)
    tile[ty + i][tx] = in[(size_t)(k0 + ty + i) * N + nn + tx];
  __syncthreads();
#pragma unroll
  for (int i = 0; i < 32; i += 8)
    out[(size_t)(n0 + ty + i) * HID + k0 + tx] = f2bf(tile[tx][ty + i]);
}

// ---------------- transpose + convert: in [K][N] f32 -> out [N][K=4096] bf16 ----------------
__global__ void transpose_convert(const float* __restrict__ in,
                                  unsigned short* __restrict__ out, int N) {
  __shared__ float tile[32][33];
  int tx = threadIdx.x, ty = threadIdx.y;       // 32 x 8
  int n0 = blockIdx.x * 32, k0 = blockIdx.y * 32;
#pragma unroll
  for (int i = 0; i < 32; i += 8)
    tile[ty + i][tx] = in[(size_t)(k0 + ty + i) * N + n0 + tx];
  __syncthreads();
#pragma unroll
  for (int i = 0; i < 32; i += 8)
    out[(size_t)(n0 + ty + i) * HID + k0 + tx] = f2bf(tile[tx][ty + i]);
}

__device__ __forceinline__ void storeC(unsigned short* C, size_t idx, float v) { C[idx] = f2bf(v); }
__device__ __forceinline__ void storeC(float* C, size_t idx, float v) { C[idx] = v; }

// ---------------- bf16 GEMM 128^2 v2 (r16-proven): O-projection (2 blocks/CU) ----------------
template <typename OutT>
__launch_bounds__(256, 2)
__global__ void gemm_bt(const unsigned short* __restrict__ A,
                        const unsigned short* __restrict__ Bt,
                        OutT* __restrict__ C, int K, int ldc) {
  __shared__ unsigned short As[2][128 * 64];   // 32 KB
  __shared__ unsigned short Bs[2][128 * 64];   // 32 KB
  const int tid = threadIdx.x, lane = tid & 63, w = tid >> 6;
  const int wr = w >> 1, wc = w & 1;
  const int m0 = blockIdx.y * 128, n0 = blockIdx.x * 128;
  const int lq = lane & 15, g = lane >> 4;
  const int sw = lq & 7;

  f32x4 acc[4][4] = {};
  const int NT = K >> 6;

  auto STAGE_PAIR = [&](int bb, int kt) {
#pragma unroll
    for (int i = 0; i < 4; ++i) {
      int ci = tid + i * 256;                  // chunk id in [0,1024)
      int r = ci >> 3;
      int jl = ((ci & 7) ^ (r & 7)) << 3;      // inverse swizzle on source
      GLOAD16(A + (size_t)(m0 + r) * K + kt + jl, &As[bb][ci * 8]);
      GLOAD16(Bt + (size_t)(n0 + r) * K + kt + jl, &Bs[bb][ci * 8]);
    }
  };

  STAGE_PAIR(0, 0);

  for (int t = 0; t < NT; ++t) {
    const int c = t & 1;
    const bool more = (t + 1) < NT;

    // ---- phase 0 (k 0..31) ----
    asm volatile("s_waitcnt vmcnt(0)" ::: "memory");   // pair(t): issued 2 phases ago
    __builtin_amdgcn_s_barrier();
    bf16x8 af[4], bf[4];
#pragma unroll
    for (int mi = 0; mi < 4; ++mi)
      af[mi] = *(const bf16x8*)&As[c][(wr * 64 + mi * 16 + lq) * 64 + ((g ^ sw) << 3)];
#pragma unroll
    for (int ni = 0; ni < 4; ++ni)
      bf[ni] = *(const bf16x8*)&Bs[c][(wc * 64 + ni * 16 + lq) * 64 + ((g ^ sw) << 3)];
    if (more) STAGE_PAIR(c ^ 1, (t + 1) << 6);
    asm volatile("s_waitcnt lgkmcnt(0)" ::: "memory");
    __builtin_amdgcn_sched_barrier(0);
    __builtin_amdgcn_s_setprio(1);
#pragma unroll
    for (int mi = 0; mi < 4; ++mi)
#pragma unroll
      for (int ni = 0; ni < 4; ++ni)
        acc[mi][ni] = __builtin_amdgcn_mfma_f32_16x16x32_bf16(af[mi], bf[ni], acc[mi][ni], 0, 0, 0);
    __builtin_amdgcn_s_setprio(0);

    // ---- phase 1 (k 32..63): same buffer, no barrier/vmcnt needed ----
#pragma unroll
    for (int mi = 0; mi < 4; ++mi)
      af[mi] = *(const bf16x8*)&As[c][(wr * 64 + mi * 16 + lq) * 64 + (((4 + g) ^ sw) << 3)];
#pragma unroll
    for (int ni = 0; ni < 4; ++ni)
      bf[ni] = *(const bf16x8*)&Bs[c][(wc * 64 + ni * 16 + lq) * 64 + (((4 + g) ^ sw) << 3)];
    asm volatile("s_waitcnt lgkmcnt(0)" ::: "memory");
    __builtin_amdgcn_sched_barrier(0);
    __builtin_amdgcn_s_setprio(1);
#pragma unroll
    for (int mi = 0; mi < 4; ++mi)
#pragma unroll
      for (int ni = 0; ni < 4; ++ni)
        acc[mi][ni] = __builtin_amdgcn_mfma_f32_16x16x32_bf16(af[mi], bf[ni], acc[mi][ni], 0, 0, 0);
    __builtin_amdgcn_s_setprio(0);
  }

  // epilogue (r3-proven indices)
#pragma unroll
  for (int mi = 0; mi < 4; ++mi) {
#pragma unroll
    for (int ni = 0; ni < 4; ++ni) {
      int row = m0 + wr * 64 + mi * 16 + g * 4;
      int col = n0 + wc * 64 + ni * 16 + lq;
#pragma unroll
      for (int r = 0; r < 4; ++r)
        storeC(C, (size_t)(row + r) * ldc + col, acc[mi][ni][r]);
    }
  }
}

// ---------------- bf16 GEMM 256x192 (r17-proven, 97us): QKV projection ----------------
template <typename OutT>
__launch_bounds__(512, 1)
__global__ void gemm_qkv(const unsigned short* __restrict__ A,
                         const unsigned short* __restrict__ Bt,
                         OutT* __restrict__ C, int K, int ldc) {
  __shared__ unsigned short As[2][256 * 64];   // 64 KB
  __shared__ unsigned short Bs[2][192 * 64];   // 48 KB
  const int tid = threadIdx.x, lane = tid & 63, w = tid >> 6;
  const int wm = w >> 2, wn = w & 3;           // 2M x 4N wave grid
  const int m0 = blockIdx.y * 256, n0 = blockIdx.x * 192;
  const int lq = lane & 15, g = lane >> 4;
  const int sw = lq & 7;

  f32x4 acc[8][3] = {};
  const int NT = K >> 6;

  auto STAGE_PAIR = [&](int bb, int kt) {
#pragma unroll
    for (int i = 0; i < 4; ++i) {              // A: 2048 chunks, 4/thread
      int ci = tid + i * 512;
      int r = ci >> 3;
      int jl = ((ci & 7) ^ (r & 7)) << 3;      // inverse swizzle on source
      GLOAD16(A + (size_t)(m0 + r) * K + kt + jl, &As[bb][ci * 8]);
    }
#pragma unroll
    for (int i = 0; i < 3; ++i) {              // B: 1536 chunks, 3/thread
      int ci = tid + i * 512;
      int r = ci >> 3;
      int jl = ((ci & 7) ^ (r & 7)) << 3;
      GLOAD16(Bt + (size_t)(n0 + r) * K + kt + jl, &Bs[bb][ci * 8]);
    }
  };

  STAGE_PAIR(0, 0);

  for (int t = 0; t < NT; ++t) {
    const int c = t & 1;
    const bool more = (t + 1) < NT;

    // ---- phase 0 (k 0..31) ----
    asm volatile("s_waitcnt vmcnt(0)" ::: "memory");   // pair(t): issued 2 phases ago
    __builtin_amdgcn_s_barrier();
    bf16x8 af[8], bf[3];
#pragma unroll
    for (int mi = 0; mi < 8; ++mi)
      af[mi] = *(const bf16x8*)&As[c][(wm * 128 + mi * 16 + lq) * 64 + ((g ^ sw) << 3)];
#pragma unroll
    for (int ni = 0; ni < 3; ++ni)
      bf[ni] = *(const bf16x8*)&Bs[c][(wn * 48 + ni * 16 + lq) * 64 + ((g ^ sw) << 3)];
    if (more) STAGE_PAIR(c ^ 1, (t + 1) << 6);
    asm volatile("s_waitcnt lgkmcnt(0)" ::: "memory");
    __builtin_amdgcn_sched_barrier(0);
    __builtin_amdgcn_s_setprio(1);
#pragma unroll
    for (int mi = 0; mi < 8; ++mi)
#pragma unroll
      for (int ni = 0; ni < 3; ++ni)
        acc[mi][ni] = __builtin_amdgcn_mfma_f32_16x16x32_bf16(af[mi], bf[ni], acc[mi][ni], 0, 0, 0);
    __builtin_amdgcn_s_setprio(0);

    // ---- phase 1 (k 32..63): same buffer, no barrier/vmcnt needed ----
#pragma unroll
    for (int mi = 0; mi < 8; ++mi)
      af[mi] = *(const bf16x8*)&As[c][(wm * 128 + mi * 16 + lq) * 64 + (((4 + g) ^ sw) << 3)];
#pragma unroll
    for (int ni = 0; ni < 3; ++ni)
      bf[ni] = *(const bf16x8*)&Bs[c][(wn * 48 + ni * 16 + lq) * 64 + (((4 + g) ^ sw) << 3)];
    asm volatile("s_waitcnt lgkmcnt(0)" ::: "memory");
    __builtin_amdgcn_sched_barrier(0);
    __builtin_amdgcn_s_setprio(1);
#pragma unroll
    for (int mi = 0; mi < 8; ++mi)
#pragma unroll
      for (int ni = 0; ni < 3; ++ni)
        acc[mi][ni] = __builtin_amdgcn_mfma_f32_16x16x32_bf16(af[mi], bf[ni], acc[mi][ni], 0, 0, 0);
    __builtin_amdgcn_s_setprio(0);
  }

  // epilogue
#pragma unroll
  for (int mi = 0; mi < 8; ++mi)
#pragma unroll
    for (int ni = 0; ni < 3; ++ni) {
      int row = m0 + wm * 128 + mi * 16 + g * 4;
      int col = n0 + wn * 48 + ni * 16 + lq;
#pragma unroll
      for (int r = 0; r < 4; ++r)
        storeC(C, (size_t)(row + r) * ldc + col, acc[mi][ni][r]);
    }
}

// ---------------- RoPE on K only (Q fused into attn prologue) ----------------
__global__ void rope_k_kernel(unsigned short* __restrict__ qkv) {
  int idx = blockIdx.x * blockDim.x + threadIdx.x;  // S * NKV * 64 pairs
  int d = idx & 63;
  int h = (idx >> 6) % NKV;
  int s = (idx >> 6) / NKV;
  size_t base = (size_t)s * QKVN + (size_t)NH * HD + (size_t)h * HD;
  float invf = __expf(-(float)d * (1.0f / 64.0f) * 9.210340371976184f);  // 10000^(-d/64)
  float ang = (float)s * invf;
  float c, sn;
  __sincosf(ang, &sn, &c);
  float x1 = bf2f(qkv[base + d]);
  float x2 = bf2f(qkv[base + d + 64]);
  qkv[base + d] = f2bf(x1 * c - x2 * sn);
  qkv[base + d + 64] = f2bf(x2 * c + x1 * sn);
}

// ---------------- flash attention v12: v11 + fused Q-RoPE in prologue ----------------
// Q is read exactly once (here), so its RoPE fuses in-register: rotate-half pair
// (d, d+64) == fragment pair (qf[0],qf[2]) / (qf[1],qf[3]) at the same (g,j).
// Attention scale folded into (cos,sin). Same rounding chain as rope_kernel
// (bf16 -> f32 rope -> f2bf). 16 sincos + 32 FMA per lane, once per block.
__launch_bounds__(512, 4)
__global__ void attn_kernel(const unsigned short* __restrict__ qkv,
                            unsigned short* __restrict__ ao) {
  __shared__ unsigned short Ks[2][64 * 128];   // 32 KB
  __shared__ unsigned short Vt[128 * 88];      // 22 KB
  __shared__ unsigned short Ps[8][16 * 88];    // 22.5 KB  (total 76 KB -> 2 blocks/CU)

  const int tid = threadIdx.x, lane = tid & 63, w = tid >> 6;  // w in 0..7
  const int b = blockIdx.x;          // 0..15
  const int h = blockIdx.y;
  const int qblk = (h < 16) ? (15 - b) : b;   // antisymmetric: CU pair sums constant
  const int kh = h >> 2;
  const int lq = lane & 15, g = lane >> 4;
  const int qbase = qblk * 128 + w * 16;
  const size_t koff = (size_t)NH * HD + (size_t)kh * HD;
  const size_t voff = (size_t)(NH + NKV) * HD + (size_t)kh * HD;

  // Q fragments: qf[ks] = Q[qbase+lq][ks*32 + g*8 ..+8]  (un-roped; roped below)
  bf16x8 qf[4];
  {
    const unsigned short* qp = qkv + (size_t)(qbase + lq) * QKVN + (size_t)h * HD + g * 8;
#pragma unroll
    for (int ks = 0; ks < 4; ++ks) qf[ks] = *(const bf16x8*)(qp + ks * 32);
  }
  // ---- fused Q-RoPE (+ attention scale), in-register ----
  {
    const float s_f = (float)(qbase + lq);
#pragma unroll
    for (int half = 0; half < 2; ++half) {
#pragma unroll
      for (int j = 0; j < 8; ++j) {
        const int d = half * 32 + g * 8 + j;
        const float invf = __expf(-(float)d * (1.0f / 64.0f) * 9.210340371976184f);
        float cc, ss;
        __sincosf(s_f * invf, &ss, &cc);
        cc *= 0.08838834764831845f;
        ss *= 0.08838834764831845f;
        const float x1 = bf2f((unsigned short)qf[half][j]);
        const float x2 = bf2f((unsigned short)qf[half + 2][j]);
        qf[half][j]     = (short)f2bf(x1 * cc - x2 * ss);
        qf[half + 2][j] = (short)f2bf(x2 * cc + x1 * ss);
      }
    }
  }

  f32x4 o[8] = {};
  float m = -1e30f;   // running max for q = qbase+lq
  float l = 0.f;      // running denom for q = qbase+lq

  // K staging: 8 waves x 2 insts; inst (w,i) covers rows (w*2+i)*4 + (lane>>4)
  auto KSTAGE = [&](int bb, int kv0) {
#pragma unroll
    for (int i = 0; i < 2; ++i) {
      int kvk = (w * 2 + i) * 4 + (lane >> 4);
      int chl = (lane & 15) ^ (kvk & 7);
      GLOAD16(qkv + (size_t)(kv0 + kvk) * QKVN + koff + chl * 8, &Ks[bb][(w * 2 + i) * 512]);
    }
  };
  // V staging by ALL 512 threads: thread covers d = vd0..vd0+3, kv = vkv..vkv+3
  const int vd0 = (tid & 31) * 4;
  const int vkv = (tid >> 5) * 4;
  u16x4 vr[4];
  auto VLOAD = [&](int kv0) {
#pragma unroll
    for (int i = 0; i < 4; ++i)
      vr[i] = *(const u16x4*)(qkv + (size_t)(kv0 + vkv + i) * QKVN + voff + vd0);
  };
  auto VWRITE = [&]() {
#pragma unroll
    for (int j = 0; j < 4; ++j) {
      const int d = vd0 + j;
      const int vswz = ((d >> 3) & 3) << 1;
      const int vcol = (((vkv >> 2) ^ vswz) << 2);
      u16x4 val = {vr[0][j], vr[1][j], vr[2][j], vr[3][j]};
      *(u16x4*)&Vt[d * 88 + vcol] = val;
    }
  };

  unsigned short* Pw = &Ps[w][0];
  const int nt = qblk * 2 + 2;   // tiles to cover rows up to qblk*128+127

  KSTAGE(0, 0);
  VLOAD(0);
  int cur = 0;
  for (int t = 0; t < nt; ++t) {
    const int kv0 = t * 64;
    __syncthreads();                    // A: K(t)/V(t) drained; prev Vt/Ks reads done
    VWRITE();
    if (t + 1 < nt) { KSTAGE(cur ^ 1, kv0 + 64); VLOAD(kv0 + 64); }

    const int nraw = qbase + 16 - kv0;            // may be <= 0 for some waves at last tile
    const int nact = nraw > 64 ? 64 : nraw;

    // ---- QK^T (swapped: sc[st][r] = S[kv=kv0+st*16+g*4+r][q=qbase+lq]) ----
    f32x4 sc[4];
    __builtin_amdgcn_s_setprio(1);
#pragma unroll
    for (int st = 0; st < 4; ++st) {
      if (st * 16 < nact) {
        f32x4 s = {};
#pragma unroll
        for (int ks = 0; ks < 4; ++ks) {
          const bf16x8 kf = *(const bf16x8*)
              &Ks[cur][(st * 16 + lq) * 128 + (((ks * 4 + g) ^ (lq & 7)) << 3)];
          s = __builtin_amdgcn_mfma_f32_16x16x32_bf16(kf, qf[ks], s, 0, 0, 0);
        }
        sc[st] = s;
      } else {
        sc[st] = (f32x4){-1e30f, -1e30f, -1e30f, -1e30f};
      }
    }
    __builtin_amdgcn_s_setprio(0);
    if (nraw < 79) {  // diagonal tile (or dead tile: fully masked, p->0 since m>-1e30)
      const int q = qbase + lq;
#pragma unroll
      for (int st = 0; st < 4; ++st) {
        int kv = kv0 + st * 16 + g * 4;
#pragma unroll
        for (int r = 0; r < 4; ++r)
          if (kv + r > q) sc[st][r] = -1e30f;
      }
    }

    // ---- online softmax: lane-local over 16 values, then 2 shfl rounds over g ----
    float mn = fmaxf(fmaxf(fmaxf(sc[0][0], sc[0][1]), fmaxf(sc[0][2], sc[0][3])),
                     fmaxf(fmaxf(sc[1][0], sc[1][1]), fmaxf(sc[1][2], sc[1][3])));
    mn = fmaxf(mn, fmaxf(fmaxf(fmaxf(sc[2][0], sc[2][1]), fmaxf(sc[2][2], sc[2][3])),
                         fmaxf(fmaxf(sc[3][0], sc[3][1]), fmaxf(sc[3][2], sc[3][3]))));
    mn = fmaxf(mn, __shfl_xor(mn, 16, 64));
    mn = fmaxf(mn, __shfl_xor(mn, 32, 64));
    const bool need = __any(mn > m);   // wave-uniform: does any lane grow its max?
    const float m2 = fmaxf(m, mn);
    const float alpha = __expf(m - m2);  // == 1.0 exactly when !need
    m = m2;
    float rs = 0.f;
#pragma unroll
    for (int st = 0; st < 4; ++st)
#pragma unroll
      for (int r = 0; r < 4; ++r) {
        float p = __expf(sc[st][r] - m2);
        sc[st][r] = p;
        rs += p;
      }
    rs += __shfl_xor(rs, 16, 64);
    rs += __shfl_xor(rs, 32, 64);
    l = l * alpha + rs;

    if (need) {  // T13: skip O-rescale when alpha==1 for all lanes (exact)
      float alphaR[4];
#pragma unroll
      for (int r = 0; r < 4; ++r) alphaR[r] = __shfl(alpha, g * 4 + r, 64);
#pragma unroll
      for (int p = 0; p < 8; ++p)
#pragma unroll
        for (int r = 0; r < 4; ++r) o[p][r] *= alphaR[r];
    }

    // ---- B: Vt(t) visible; raw barrier, NO vmcnt drain (prefetch stays in flight) ----
    asm volatile("s_waitcnt lgkmcnt(0)" ::: "memory");
    __builtin_amdgcn_s_barrier();
    __builtin_amdgcn_sched_barrier(0);

    // ---- P -> LDS via v_cvt_pk_bf16_f32 (RNE, 2 f32/inst) ----
#pragma unroll
    for (int st = 0; st < 4; ++st) {
      unsigned r01, r23;
      asm("v_cvt_pk_bf16_f32 %0, %1, %2" : "=v"(r01) : "v"(sc[st][0]), "v"(sc[st][1]));
      asm("v_cvt_pk_bf16_f32 %0, %1, %2" : "=v"(r23) : "v"(sc[st][2]), "v"(sc[st][3]));
      unsigned* dst = (unsigned*)&Pw[lq * 88 + st * 16 + g * 4];
      dst[0] = r01; dst[1] = r23;
    }

    // ---- O += P V ----
    const int nks = nact > 0 ? (nact + 31) >> 5 : 0;
    __builtin_amdgcn_s_setprio(1);
    for (int ks = 0; ks < nks; ++ks) {
      const bf16x8 pf = *(const bf16x8*)&Pw[lq * 88 + ks * 32 + g * 8];
#pragma unroll
      for (int p = 0; p < 8; ++p) {
        const int d = p * 16 + lq;
        const int rswz = ((d >> 3) & 3) << 1;
        const int kvc = (ks * 8 + g * 2) ^ rswz;
        const bf16x8 vf = *(const bf16x8*)&Vt[d * 88 + (kvc << 2)];
        o[p] = __builtin_amdgcn_mfma_f32_16x16x32_bf16(pf, vf, o[p], 0, 0, 0);
      }
    }
    __builtin_amdgcn_s_setprio(0);

    cur ^= 1;
  }

  // epilogue: O / l -> ao (bf16, [s][NH*HD]); l for row g*4+r from lane lq=g*4+r
  float invR[4];
#pragma unroll
  for (int r = 0; r < 4; ++r) invR[r] = 1.0f / __shfl(l, g * 4 + r, 64);
#pragma unroll
  for (int p = 0; p < 8; ++p)
#pragma unroll
    for (int r = 0; r < 4; ++r)
      ao[(size_t)(qbase + g * 4 + r) * (NH * HD) + (size_t)h * HD + p * 16 + lq] =
          f2bf(o[p][r] * invR[r]);
}

extern "C" void kernel_launch(void* const* d_in, const int* in_sizes, int n_in,
                              void* d_out, int out_size, void* d_ws, size_t ws_size,
                              hipStream_t stream) {
  const float* X  = (const float*)d_in[0];
  const float* qw = (const float*)d_in[2];
  const float* kw = (const float*)d_in[3];
  const float* vw = (const float*)d_in[4];
  const float* ow = (const float*)d_in[5];
  float* out = (float*)d_out;

  char* ws = (char*)d_ws;
  unsigned short* Xb  = (unsigned short*)(ws);
  unsigned short* Wt  = (unsigned short*)(ws + (size_t)(16u << 20));
  unsigned short* QKV = (unsigned short*)(ws + (size_t)(64u << 20));
  unsigned short* AO  = (unsigned short*)(ws + (size_t)(88u << 20));
  unsigned short* OWt = (unsigned short*)(ws);

  dim3 tb(32, 8);

  convert_kernel<<<(S * HID / 4 + 255) / 256, 256, 0, stream>>>(X, Xb, S * HID / 4);
  transpose_qkv<<<dim3(QKVN / 32, HID / 32), tb, 0, stream>>>(qw, kw, vw, Wt);
  gemm_qkv<unsigned short><<<dim3(QKVN / 192, S / 256), 512, 0, stream>>>(Xb, Wt, QKV, HID, QKVN);
  transpose_convert<<<dim3(HID / 32, HID / 32), tb, 0, stream>>>(ow, OWt, HID);
  // RoPE on K only (Q-RoPE fused into attn prologue)
  rope_k_kernel<<<(S * NKV * 64) / 256, 256, 0, stream>>>(QKV);
  attn_kernel<<<dim3(16, NH), 512, 0, stream>>>(QKV, AO);
  gemm_bt<float><<<dim3(HID / 128, S / 128), 256, 0, stream>>>(AO, OWt, out, HID, HID);
}